// Round 2
// baseline (664.611 us; speedup 1.0000x reference)
//
#include <hip/hip_runtime.h>
#include <hip/hip_bf16.h>

#define N_NODES 100000
#define N_EDGES 800000
#define D 64
#define SCAN_B 256
#define NB1 ((N_NODES + SCAN_B - 1) / SCAN_B)   // 391 blocks

// ---------------------------------------------------------------------------
// embeds[node][d] = node_emb[nodes[node]][d] + features[node] . feat_W[d] + feat_b[d]
__global__ void init_embeds_kernel(const int* __restrict__ nodes,
                                   const float* __restrict__ features,
                                   const float* __restrict__ node_emb,
                                   const float* __restrict__ feat_W,
                                   const float* __restrict__ feat_b,
                                   float* __restrict__ embeds) {
    int tid = blockIdx.x * blockDim.x + threadIdx.x;
    if (tid >= N_NODES * D) return;
    int node = tid >> 6;
    int d = tid & 63;
    float acc = feat_b[d];
    const float* f = features + (size_t)node * 10;
    const float* w = feat_W + (size_t)d * 10;
#pragma unroll
    for (int j = 0; j < 10; ++j) acc += f[j] * w[j];
    embeds[tid] = node_emb[(size_t)nodes[node] * D + d] + acc;
}

// ---------------------------------------------------------------------------
// CSR build: histogram of dst degrees (int atomics, 64x fewer than before)
__global__ void hist_kernel(const int* __restrict__ edges, int* __restrict__ deg) {
    int t = blockIdx.x * blockDim.x + threadIdx.x;
    if (t < N_EDGES) {
        int dst = ((const int2*)edges)[t].y;
        atomicAdd(&deg[dst], 1);
    }
}

// Block-local exclusive scan (Hillis-Steele over 256), emits block totals.
__global__ void scan1_kernel(const int* __restrict__ deg,
                             int* __restrict__ row_ptr,
                             int* __restrict__ bsum) {
    __shared__ int tmp[SCAN_B];
    int t = threadIdx.x;
    int i = blockIdx.x * SCAN_B + t;
    int v = (i < N_NODES) ? deg[i] : 0;
    tmp[t] = v;
    __syncthreads();
#pragma unroll
    for (int off = 1; off < SCAN_B; off <<= 1) {
        int a = (t >= off) ? tmp[t - off] : 0;
        __syncthreads();
        tmp[t] += a;
        __syncthreads();
    }
    if (i < N_NODES) row_ptr[i] = tmp[t] - v;   // exclusive
    if (t == SCAN_B - 1) bsum[blockIdx.x] = tmp[t];
}

// Exclusive scan of the 391 block totals (single block, 512 threads).
__global__ void scan2_kernel(const int* __restrict__ bsum, int* __restrict__ boff) {
    __shared__ int tmp[512];
    int t = threadIdx.x;
    int v = (t < NB1) ? bsum[t] : 0;
    tmp[t] = v;
    __syncthreads();
#pragma unroll
    for (int off = 1; off < 512; off <<= 1) {
        int a = (t >= off) ? tmp[t - off] : 0;
        __syncthreads();
        tmp[t] += a;
        __syncthreads();
    }
    if (t < NB1) boff[t] = tmp[t] - v;
}

// Add block offsets; duplicate into cursor; close the row_ptr.
__global__ void scan3_kernel(int* __restrict__ row_ptr,
                             const int* __restrict__ boff,
                             int* __restrict__ cursor) {
    int i = blockIdx.x * SCAN_B + threadIdx.x;
    if (i < N_NODES) {
        int r = row_ptr[i] + boff[i >> 8];
        row_ptr[i] = r;
        cursor[i] = r;
    }
    if (i == 0) row_ptr[N_NODES] = N_EDGES;
}

// Scatter edge srcs into CSR column array.
__global__ void fill_kernel(const int* __restrict__ edges,
                            int* __restrict__ cursor,
                            int* __restrict__ col) {
    int t = blockIdx.x * blockDim.x + threadIdx.x;
    if (t < N_EDGES) {
        int2 e = ((const int2*)edges)[t];
        int pos = atomicAdd(&cursor[e.y], 1);
        col[pos] = e.x;
    }
}

// ---------------------------------------------------------------------------
// Fused: agg-gather + (embeds+agg) @ W^T + b, ReLU. One wave per dst node.
// Lane d holds W row d in 16 float4 VGPRs; x broadcast via ds_read_b128.
__global__ void agg_conv_kernel(const float* __restrict__ emb_in,
                                const int* __restrict__ row_ptr,
                                const int* __restrict__ col,
                                const float* __restrict__ W,
                                const float* __restrict__ b,
                                float* __restrict__ emb_out) {
    __shared__ float xs[4][D];
    int lane = threadIdx.x & 63;
    int wv = threadIdx.x >> 6;
    int node = blockIdx.x * 4 + wv;   // grid = 25000 blocks * 4 waves = exactly N_NODES

    // W row `lane` -> registers (16 KB total, L2-hot after first blocks)
    float4 Wr[16];
    const float4* W4 = (const float4*)(W + (size_t)lane * D);
#pragma unroll
    for (int i = 0; i < 16; ++i) Wr[i] = W4[i];

    int start = row_ptr[node];
    int end = row_ptr[node + 1];
    float acc = emb_in[(size_t)node * D + lane];   // self term (embeds + agg)

    int e = start;
    for (; e + 4 <= end; e += 4) {                 // unroll-4: independent row loads
        int s0 = col[e], s1 = col[e + 1], s2 = col[e + 2], s3 = col[e + 3];
        float v0 = emb_in[(size_t)s0 * D + lane];
        float v1 = emb_in[(size_t)s1 * D + lane];
        float v2 = emb_in[(size_t)s2 * D + lane];
        float v3 = emb_in[(size_t)s3 * D + lane];
        acc += (v0 + v1) + (v2 + v3);
    }
    for (; e < end; ++e) acc += emb_in[(size_t)col[e] * D + lane];

    xs[wv][lane] = acc;
    __syncthreads();   // all 25000*4 waves uniform, no early return — safe

    float y = b[lane];
    const float4* xv = (const float4*)xs[wv];
#pragma unroll
    for (int i = 0; i < 16; ++i) {
        float4 x4 = xv[i];                          // ds_read_b128 broadcast (free)
        y += Wr[i].x * x4.x + Wr[i].y * x4.y + Wr[i].z * x4.z + Wr[i].w * x4.w;
    }
    emb_out[(size_t)node * D + lane] = fmaxf(y, 0.0f);
}

// ---------------------------------------------------------------------------
// out[node] = cos_sim(embeds[node], pattern_emb[pattern_id])
__global__ void final_score_kernel(const float* __restrict__ embeds,
                                   const float* __restrict__ pattern_emb,
                                   const int* __restrict__ pattern_id,
                                   float* __restrict__ out) {
    int lane = threadIdx.x & 63;
    int wave = threadIdx.x >> 6;
    int node = blockIdx.x * 4 + wave;
    int pid = pattern_id[0];
    float p = pattern_emb[(size_t)pid * D + lane];

    float pn = p * p;
#pragma unroll
    for (int m = 32; m > 0; m >>= 1) pn += __shfl_xor(pn, m, 64);

    if (node < N_NODES) {
        float e = embeds[(size_t)node * D + lane];
        float dot = e * p;
        float n2 = e * e;
#pragma unroll
        for (int m = 32; m > 0; m >>= 1) {
            dot += __shfl_xor(dot, m, 64);
            n2  += __shfl_xor(n2, m, 64);
        }
        if (lane == 0) {
            float denom = fmaxf(sqrtf(n2), 1e-8f) * fmaxf(sqrtf(pn), 1e-8f);
            out[node] = dot / denom;
        }
    }
}

// ---------------------------------------------------------------------------
// Fallback path (round-1 kernels) in case ws_size can't fit CSR arrays.
__global__ void scatter_add_kernel(const int* __restrict__ edges,
                                   const float* __restrict__ embeds,
                                   float* __restrict__ agg) {
    int tid = blockIdx.x * blockDim.x + threadIdx.x;
    int edge = tid >> 6;
    int lane = tid & 63;
    if (edge >= N_EDGES) return;
    int src = edges[2 * edge + 0];
    int dst = edges[2 * edge + 1];
    atomicAdd(&agg[(size_t)dst * D + lane], embeds[(size_t)src * D + lane]);
}

__global__ void conv_update_kernel(const float* __restrict__ agg,
                                   const float* __restrict__ W,
                                   const float* __restrict__ b,
                                   float* __restrict__ embeds) {
    __shared__ float Ws[D * 65];
    __shared__ float xs[4][D];
    for (int i = threadIdx.x; i < D * D; i += blockDim.x) {
        int d = i >> 6, k = i & 63;
        Ws[d * 65 + k] = W[i];
    }
    __syncthreads();
    int lane_d = threadIdx.x & 63;
    int local_n = threadIdx.x >> 6;
    float bias = b[lane_d];
    const int n_chunks = (N_NODES + 3) / 4;
    for (int chunk = blockIdx.x; chunk < n_chunks; chunk += gridDim.x) {
        int node = chunk * 4 + local_n;
        if (node < N_NODES) {
            size_t base = (size_t)node * D + lane_d;
            xs[local_n][lane_d] = embeds[base] + agg[base];
        }
        __syncthreads();
        if (node < N_NODES) {
            float acc = bias;
#pragma unroll
            for (int k = 0; k < D; ++k) acc += xs[local_n][k] * Ws[lane_d * 65 + k];
            embeds[(size_t)node * D + lane_d] = fmaxf(acc, 0.0f);
        }
        __syncthreads();
    }
}

// ---------------------------------------------------------------------------
extern "C" void kernel_launch(void* const* d_in, const int* in_sizes, int n_in,
                              void* d_out, int out_size, void* d_ws, size_t ws_size,
                              hipStream_t stream) {
    const int*   nodes       = (const int*)d_in[0];
    const int*   edges       = (const int*)d_in[1];
    const float* features    = (const float*)d_in[2];
    const float* node_emb    = (const float*)d_in[3];
    const float* feat_W      = (const float*)d_in[4];
    const float* feat_b      = (const float*)d_in[5];
    const float* conv1_W     = (const float*)d_in[6];
    const float* conv1_b     = (const float*)d_in[7];
    const float* pattern_emb = (const float*)d_in[8];
    const int*   pattern_id  = (const int*)d_in[9];
    float* out = (float*)d_out;

    const size_t emb_bytes = (size_t)N_NODES * D * sizeof(float);       // 25.6 MB
    auto align256 = [](size_t x) { return (x + 255) & ~(size_t)255; };

    // CSR-path workspace layout
    size_t o_embA = 0;
    size_t o_embB = o_embA + align256(emb_bytes);
    size_t o_col  = o_embB + align256(emb_bytes);
    size_t o_row  = o_col  + align256((size_t)N_EDGES * 4);
    size_t o_deg  = o_row  + align256((size_t)(N_NODES + 1) * 4);       // deg aliases cursor
    size_t o_bsum = o_deg  + align256((size_t)N_NODES * 4);
    size_t o_boff = o_bsum + align256((size_t)NB1 * 4);
    size_t need   = o_boff + align256((size_t)NB1 * 4);

    char* ws = (char*)d_ws;

    if (ws_size >= need) {
        float* embA   = (float*)(ws + o_embA);
        float* embB   = (float*)(ws + o_embB);
        int*   col    = (int*)(ws + o_col);
        int*   rowp   = (int*)(ws + o_row);
        int*   degcur = (int*)(ws + o_deg);   // deg during build, then cursor
        int*   bsum   = (int*)(ws + o_bsum);
        int*   boff   = (int*)(ws + o_boff);

        // init embeds
        init_embeds_kernel<<<(N_NODES * D + 255) / 256, 256, 0, stream>>>(
            nodes, features, node_emb, feat_W, feat_b, embA);

        // CSR build (once per call)
        hipMemsetAsync(degcur, 0, (size_t)N_NODES * 4, stream);
        hist_kernel<<<(N_EDGES + 255) / 256, 256, 0, stream>>>(edges, degcur);
        scan1_kernel<<<NB1, SCAN_B, 0, stream>>>(degcur, rowp, bsum);
        scan2_kernel<<<1, 512, 0, stream>>>(bsum, boff);
        scan3_kernel<<<NB1, SCAN_B, 0, stream>>>(rowp, boff, degcur);   // degcur now = cursor
        fill_kernel<<<(N_EDGES + 255) / 256, 256, 0, stream>>>(edges, degcur, col);

        // two fused conv iterations, ping-pong
        agg_conv_kernel<<<N_NODES / 4, 256, 0, stream>>>(embA, rowp, col, conv1_W, conv1_b, embB);
        agg_conv_kernel<<<N_NODES / 4, 256, 0, stream>>>(embB, rowp, col, conv1_W, conv1_b, embA);

        final_score_kernel<<<(N_NODES + 3) / 4, 256, 0, stream>>>(
            embA, pattern_emb, pattern_id, out);
    } else {
        // fallback: round-1 atomic-scatter path (needs only 2 x emb_bytes)
        float* embeds = (float*)ws;
        float* agg = (float*)(ws + align256(emb_bytes));
        init_embeds_kernel<<<(N_NODES * D + 255) / 256, 256, 0, stream>>>(
            nodes, features, node_emb, feat_W, feat_b, embeds);
        for (int it = 0; it < 2; ++it) {
            hipMemsetAsync(agg, 0, emb_bytes, stream);
            long long total = (long long)N_EDGES * 64;
            scatter_add_kernel<<<(int)((total + 255) / 256), 256, 0, stream>>>(edges, embeds, agg);
            conv_update_kernel<<<2048, 256, 0, stream>>>(agg, conv1_W, conv1_b, embeds);
        }
        final_score_kernel<<<(N_NODES + 3) / 4, 256, 0, stream>>>(
            embeds, pattern_emb, pattern_id, out);
    }
}

// Round 3
// 352.792 us; speedup vs baseline: 1.8839x; 1.8839x over previous
//
#include <hip/hip_runtime.h>
#include <hip/hip_bf16.h>

#define N_NODES 100000
#define N_EDGES 800000
#define D 64
#define SCAN_B 256
#define NB1 ((N_NODES + SCAN_B - 1) / SCAN_B)   // 391 blocks

// ---------------------------------------------------------------------------
// embeds[node][d] = node_emb[nodes[node]][d] + features[node] . feat_W[d] + feat_b[d]
__global__ void init_embeds_kernel(const int* __restrict__ nodes,
                                   const float* __restrict__ features,
                                   const float* __restrict__ node_emb,
                                   const float* __restrict__ feat_W,
                                   const float* __restrict__ feat_b,
                                   float* __restrict__ embeds) {
    int tid = blockIdx.x * blockDim.x + threadIdx.x;
    if (tid >= N_NODES * D) return;
    int node = tid >> 6;
    int d = tid & 63;
    float acc = feat_b[d];
    const float* f = features + (size_t)node * 10;
    const float* w = feat_W + (size_t)d * 10;
#pragma unroll
    for (int j = 0; j < 10; ++j) acc += f[j] * w[j];
    embeds[tid] = node_emb[(size_t)nodes[node] * D + d] + acc;
}

// ---------------------------------------------------------------------------
// CSR build
__global__ void hist_kernel(const int* __restrict__ edges, int* __restrict__ deg) {
    int t = blockIdx.x * blockDim.x + threadIdx.x;
    if (t < N_EDGES) {
        int dst = ((const int2*)edges)[t].y;
        atomicAdd(&deg[dst], 1);
    }
}

__global__ void scan1_kernel(const int* __restrict__ deg,
                             int* __restrict__ row_ptr,
                             int* __restrict__ bsum) {
    __shared__ int tmp[SCAN_B];
    int t = threadIdx.x;
    int i = blockIdx.x * SCAN_B + t;
    int v = (i < N_NODES) ? deg[i] : 0;
    tmp[t] = v;
    __syncthreads();
#pragma unroll
    for (int off = 1; off < SCAN_B; off <<= 1) {
        int a = (t >= off) ? tmp[t - off] : 0;
        __syncthreads();
        tmp[t] += a;
        __syncthreads();
    }
    if (i < N_NODES) row_ptr[i] = tmp[t] - v;   // exclusive
    if (t == SCAN_B - 1) bsum[blockIdx.x] = tmp[t];
}

__global__ void scan2_kernel(const int* __restrict__ bsum, int* __restrict__ boff) {
    __shared__ int tmp[512];
    int t = threadIdx.x;
    int v = (t < NB1) ? bsum[t] : 0;
    tmp[t] = v;
    __syncthreads();
#pragma unroll
    for (int off = 1; off < 512; off <<= 1) {
        int a = (t >= off) ? tmp[t - off] : 0;
        __syncthreads();
        tmp[t] += a;
        __syncthreads();
    }
    if (t < NB1) boff[t] = tmp[t] - v;
}

__global__ void scan3_kernel(int* __restrict__ row_ptr,
                             const int* __restrict__ boff,
                             int* __restrict__ cursor) {
    int i = blockIdx.x * SCAN_B + threadIdx.x;
    if (i < N_NODES) {
        int r = row_ptr[i] + boff[i >> 8];
        row_ptr[i] = r;
        cursor[i] = r;
    }
    if (i == 0) row_ptr[N_NODES] = N_EDGES;
}

__global__ void fill_kernel(const int* __restrict__ edges,
                            int* __restrict__ cursor,
                            int* __restrict__ col) {
    int t = blockIdx.x * blockDim.x + threadIdx.x;
    if (t < N_EDGES) {
        int2 e = ((const int2*)edges)[t];
        int pos = atomicAdd(&cursor[e.y], 1);
        col[pos] = e.x;
    }
}

// ---------------------------------------------------------------------------
// x[node] = emb_in[node] + sum_{src in N(node)} emb_in[src]
// One wave per node. 4 groups x 16 lanes: each group gathers a different src
// row (lane = float4 chunk) -> 4 rows in flight per load instruction.
__global__ __launch_bounds__(256) void gather_x_kernel(
        const float* __restrict__ emb_in,
        const int* __restrict__ row_ptr,
        const int* __restrict__ col,
        float* __restrict__ x_out) {
    int lane = threadIdx.x & 63;
    int wv   = threadIdx.x >> 6;
    int node = blockIdx.x * 4 + wv;          // grid = 25000, exact
    int g = lane >> 4;                        // row-group 0..3
    int c = lane & 15;                        // float4 chunk 0..15

    int start = row_ptr[node];
    int end   = row_ptr[node + 1];

    float4 acc = make_float4(0.f, 0.f, 0.f, 0.f);
    if (g == 0)                               // self term, counted once
        acc = ((const float4*)(emb_in + (size_t)node * D))[c];

    for (int base = start; base < end; base += 64) {
        int nb = end - base; if (nb > 64) nb = 64;
        int idx = (lane < nb) ? col[base + lane] : 0;   // one vector load, <=64 idx
        int rounds = (nb + 3) >> 2;                     // uniform trip count
        for (int r = 0; r < rounds; ++r) {
            int s = r * 4 + g;                          // s <= 63 always
            int src = __shfl(idx, s, 64);               // all lanes active
            if (s < nb) {
                float4 v = ((const float4*)(emb_in + (size_t)src * D))[c];
                acc.x += v.x; acc.y += v.y; acc.z += v.z; acc.w += v.w;
            }
        }
    }

    // combine the 4 group partials (xor 16, 32)
    acc.x += __shfl_xor(acc.x, 16, 64); acc.y += __shfl_xor(acc.y, 16, 64);
    acc.z += __shfl_xor(acc.z, 16, 64); acc.w += __shfl_xor(acc.w, 16, 64);
    acc.x += __shfl_xor(acc.x, 32, 64); acc.y += __shfl_xor(acc.y, 32, 64);
    acc.z += __shfl_xor(acc.z, 32, 64); acc.w += __shfl_xor(acc.w, 32, 64);

    if (g == 0)                               // 16 lanes x 16 B = full 256 B row
        ((float4*)(x_out + (size_t)node * D))[c] = acc;
}

// ---------------------------------------------------------------------------
// emb_out = relu(x @ W^T + b). W staged in LDS, stride 68 floats:
// b128 read bank = (4*lane + 4*k4) % 32 -> conflict-free tiling.
__global__ __launch_bounds__(256) void conv_update_kernel(
        const float* __restrict__ x,
        const float* __restrict__ W,
        const float* __restrict__ b,
        float* __restrict__ emb_out) {
    __shared__ float Ws[D * 68];
    __shared__ float4 xs[4][16];

    for (int i = threadIdx.x; i < D * D; i += 256) {
        int d = i >> 6, k = i & 63;
        Ws[d * 68 + k] = W[i];
    }
    __syncthreads();

    int lane = threadIdx.x & 63;
    int wv   = threadIdx.x >> 6;
    float bias = b[lane];
    const float4* Wrow = (const float4*)(Ws + lane * 68);

    // Try to keep W row in VGPRs across the chunk loop.
    float4 Wr[16];
#pragma unroll
    for (int k4 = 0; k4 < 16; ++k4) Wr[k4] = Wrow[k4];

    const int n_chunks = N_NODES / 4;         // 25000, exact
    for (int chunk = blockIdx.x; chunk < n_chunks; chunk += gridDim.x) {
        int node = chunk * 4 + wv;
        if (lane < 16)
            xs[wv][lane] = ((const float4*)(x + (size_t)node * D))[lane];
        // intra-wave producer->consumer through LDS: drain loads, order ds ops
        asm volatile("s_waitcnt vmcnt(0) lgkmcnt(0)" ::: "memory");
        float y = bias;
#pragma unroll
        for (int k4 = 0; k4 < 16; ++k4) {
            float4 x4 = xs[wv][k4];           // broadcast ds_read_b128 (free)
            y += Wr[k4].x * x4.x + Wr[k4].y * x4.y + Wr[k4].z * x4.z + Wr[k4].w * x4.w;
        }
        emb_out[(size_t)node * D + lane] = fmaxf(y, 0.0f);
    }
}

// ---------------------------------------------------------------------------
__global__ void final_score_kernel(const float* __restrict__ embeds,
                                   const float* __restrict__ pattern_emb,
                                   const int* __restrict__ pattern_id,
                                   float* __restrict__ out) {
    int lane = threadIdx.x & 63;
    int wave = threadIdx.x >> 6;
    int node = blockIdx.x * 4 + wave;
    int pid = pattern_id[0];
    float p = pattern_emb[(size_t)pid * D + lane];

    float pn = p * p;
#pragma unroll
    for (int m = 32; m > 0; m >>= 1) pn += __shfl_xor(pn, m, 64);

    if (node < N_NODES) {
        float e = embeds[(size_t)node * D + lane];
        float dot = e * p;
        float n2 = e * e;
#pragma unroll
        for (int m = 32; m > 0; m >>= 1) {
            dot += __shfl_xor(dot, m, 64);
            n2  += __shfl_xor(n2, m, 64);
        }
        if (lane == 0) {
            float denom = fmaxf(sqrtf(n2), 1e-8f) * fmaxf(sqrtf(pn), 1e-8f);
            out[node] = dot / denom;
        }
    }
}

// ---------------------------------------------------------------------------
// Fallback (atomic scatter) if ws too small for CSR arrays.
__global__ void scatter_add_kernel(const int* __restrict__ edges,
                                   const float* __restrict__ embeds,
                                   float* __restrict__ agg) {
    int tid = blockIdx.x * blockDim.x + threadIdx.x;
    int edge = tid >> 6;
    int lane = tid & 63;
    if (edge >= N_EDGES) return;
    int src = edges[2 * edge + 0];
    int dst = edges[2 * edge + 1];
    atomicAdd(&agg[(size_t)dst * D + lane], embeds[(size_t)src * D + lane]);
}

__global__ void conv_inplace_kernel(const float* __restrict__ agg,
                                    const float* __restrict__ W,
                                    const float* __restrict__ b,
                                    float* __restrict__ embeds) {
    __shared__ float Ws[D * 65];
    __shared__ float xs[4][D];
    for (int i = threadIdx.x; i < D * D; i += blockDim.x) {
        int d = i >> 6, k = i & 63;
        Ws[d * 65 + k] = W[i];
    }
    __syncthreads();
    int lane_d = threadIdx.x & 63;
    int local_n = threadIdx.x >> 6;
    float bias = b[lane_d];
    const int n_chunks = (N_NODES + 3) / 4;
    for (int chunk = blockIdx.x; chunk < n_chunks; chunk += gridDim.x) {
        int node = chunk * 4 + local_n;
        if (node < N_NODES) {
            size_t base = (size_t)node * D + lane_d;
            xs[local_n][lane_d] = embeds[base] + agg[base];
        }
        __syncthreads();
        if (node < N_NODES) {
            float acc = bias;
#pragma unroll
            for (int k = 0; k < D; ++k) acc += xs[local_n][k] * Ws[lane_d * 65 + k];
            embeds[(size_t)node * D + lane_d] = fmaxf(acc, 0.0f);
        }
        __syncthreads();
    }
}

// ---------------------------------------------------------------------------
extern "C" void kernel_launch(void* const* d_in, const int* in_sizes, int n_in,
                              void* d_out, int out_size, void* d_ws, size_t ws_size,
                              hipStream_t stream) {
    const int*   nodes       = (const int*)d_in[0];
    const int*   edges       = (const int*)d_in[1];
    const float* features    = (const float*)d_in[2];
    const float* node_emb    = (const float*)d_in[3];
    const float* feat_W      = (const float*)d_in[4];
    const float* feat_b      = (const float*)d_in[5];
    const float* conv1_W     = (const float*)d_in[6];
    const float* conv1_b     = (const float*)d_in[7];
    const float* pattern_emb = (const float*)d_in[8];
    const int*   pattern_id  = (const int*)d_in[9];
    float* out = (float*)d_out;

    const size_t emb_bytes = (size_t)N_NODES * D * sizeof(float);       // 25.6 MB
    auto align256 = [](size_t x) { return (x + 255) & ~(size_t)255; };

    size_t o_embA = 0;
    size_t o_embB = o_embA + align256(emb_bytes);
    size_t o_col  = o_embB + align256(emb_bytes);
    size_t o_row  = o_col  + align256((size_t)N_EDGES * 4);
    size_t o_deg  = o_row  + align256((size_t)(N_NODES + 1) * 4);
    size_t o_bsum = o_deg  + align256((size_t)N_NODES * 4);
    size_t o_boff = o_bsum + align256((size_t)NB1 * 4);
    size_t need   = o_boff + align256((size_t)NB1 * 4);

    char* ws = (char*)d_ws;

    if (ws_size >= need) {
        float* embA   = (float*)(ws + o_embA);
        float* embB   = (float*)(ws + o_embB);   // doubles as x buffer
        int*   col    = (int*)(ws + o_col);
        int*   rowp   = (int*)(ws + o_row);
        int*   degcur = (int*)(ws + o_deg);
        int*   bsum   = (int*)(ws + o_bsum);
        int*   boff   = (int*)(ws + o_boff);

        init_embeds_kernel<<<(N_NODES * D + 255) / 256, 256, 0, stream>>>(
            nodes, features, node_emb, feat_W, feat_b, embA);

        hipMemsetAsync(degcur, 0, (size_t)N_NODES * 4, stream);
        hist_kernel<<<(N_EDGES + 255) / 256, 256, 0, stream>>>(edges, degcur);
        scan1_kernel<<<NB1, SCAN_B, 0, stream>>>(degcur, rowp, bsum);
        scan2_kernel<<<1, 512, 0, stream>>>(bsum, boff);
        scan3_kernel<<<NB1, SCAN_B, 0, stream>>>(rowp, boff, degcur);
        fill_kernel<<<(N_EDGES + 255) / 256, 256, 0, stream>>>(edges, degcur, col);

        for (int it = 0; it < 2; ++it) {
            gather_x_kernel<<<N_NODES / 4, 256, 0, stream>>>(embA, rowp, col, embB);
            conv_update_kernel<<<2048, 256, 0, stream>>>(embB, conv1_W, conv1_b, embA);
        }

        final_score_kernel<<<(N_NODES + 3) / 4, 256, 0, stream>>>(
            embA, pattern_emb, pattern_id, out);
    } else {
        float* embeds = (float*)ws;
        float* agg = (float*)(ws + align256(emb_bytes));
        init_embeds_kernel<<<(N_NODES * D + 255) / 256, 256, 0, stream>>>(
            nodes, features, node_emb, feat_W, feat_b, embeds);
        for (int it = 0; it < 2; ++it) {
            hipMemsetAsync(agg, 0, emb_bytes, stream);
            long long total = (long long)N_EDGES * 64;
            scatter_add_kernel<<<(int)((total + 255) / 256), 256, 0, stream>>>(edges, embeds, agg);
            conv_inplace_kernel<<<2048, 256, 0, stream>>>(agg, conv1_W, conv1_b, embeds);
        }
        final_score_kernel<<<(N_NODES + 3) / 4, 256, 0, stream>>>(
            embeds, pattern_emb, pattern_id, out);
    }
}